// Round 5
// baseline (312.920 us; speedup 1.0000x reference)
//
#include <hip/hip_runtime.h>
#include <stdint.h>

#define EMB 256
#define LDK 288   // padded K for h_e / wT (266 -> 288, multiple of 32)
#define DDE 10

typedef __attribute__((ext_vector_type(8))) short short8;
typedef __attribute__((ext_vector_type(4))) float f32x4;
typedef __attribute__((ext_vector_type(4))) int int4v;

__device__ __forceinline__ unsigned short f2bf(float f) {
    union { float f; unsigned int u; } v; v.f = f;
    unsigned int u = v.u;
    unsigned int r = (u + 0x7FFFu + ((u >> 16) & 1u)) >> 16;  // RNE
    return (unsigned short)r;
}
__device__ __forceinline__ float bf2f(unsigned short b) {
    union { unsigned int u; float f; } v; v.u = ((unsigned int)b) << 16;
    return v.f;
}

// ---- fixed-point packed scatter ----
// u64 fields: s0 in [36,62), s1 in [10,36), deg in [0,10). values in [0,1),
// scaled 2^20; deg <= 1023, field sums stay < 2^26 -> no cross-field carry.
#define FPSCALE 1048576.0f
#define FPINV   (1.0f / 1048576.0f)

__device__ __forceinline__ unsigned long long pack2(float a, float b) {
    unsigned int ua = (unsigned int)(a * FPSCALE);
    unsigned int ub = (unsigned int)(b * FPSCALE);
    return ((unsigned long long)ua << 36) | ((unsigned long long)ub << 10);
}
__device__ __forceinline__ float2 unpack2(unsigned long long v) {
    float d = fmaxf((float)(unsigned int)(v & 0x3FFULL), 1.0f);
    return make_float2((float)((v >> 36) & 0x3FFFFFFULL) * FPINV / d,
                       (float)((v >> 10) & 0x3FFFFFFULL) * FPINV / d);
}
__device__ __forceinline__ float2 unpack2d(unsigned long long v, float d) {
    return make_float2((float)((v >> 36) & 0x3FFFFFFULL) * FPINV / d,
                       (float)((v >> 10) & 0x3FFFFFFULL) * FPINV / d);
}

// ---------------- mega kernel 1: scatter r1 + he copy + wT build + Pr build ----------------

__global__ void k_r1_fused(const int* __restrict__ h_id, const int* __restrict__ t_id,
                           const float2* __restrict__ topic,
                           unsigned long long* __restrict__ fwd,
                           unsigned long long* __restrict__ rev, int E, int SC1, int COPY, int WT_BLK,
                           const float4* __restrict__ entity, const float4* __restrict__ nontext,
                           ushort4* __restrict__ he4, int n_text, int N,
                           const float* __restrict__ W1, unsigned short* __restrict__ wT,
                           const float* __restrict__ qv, const float* __restrict__ rel,
                           const float* __restrict__ b1, unsigned short* __restrict__ Prb) {
    int b = blockIdx.x;
    if (b < SC1) {
        int e = b * 256 + threadIdx.x;
        if (e >= E) return;
        int h = h_id[e], t = t_id[e];
        float2 th = topic[h];
        float2 tt = topic[t];
        atomicAdd(&fwd[t], pack2(th.x, th.y) | 1ULL);
        atomicAdd(&rev[h], pack2(tt.x, tt.y) | 1ULL);
    } else if (b < SC1 + COPY) {
        // h_e columns 0..255 (64 float4 chunks per row)
        int idx = (b - SC1) * 256 + threadIdx.x;   // < Mpad*64 exactly
        int n = idx >> 6, q = idx & 63;
        float4 v = make_float4(0.f, 0.f, 0.f, 0.f);
        if (n < N) v = (n < n_text) ? entity[(size_t)n * 64 + q] : nontext[q];
        he4[(size_t)n * (LDK / 4) + q] = make_ushort4(f2bf(v.x), f2bf(v.y), f2bf(v.z), f2bf(v.w));
    } else if (b < SC1 + COPY + WT_BLK) {
        // wT[j][k]: j<256 -> col j of W1 rows 256..521; j>=256 -> col j-256 rows 778..1043
        int idx = (b - SC1 - COPY) * 256 + threadIdx.x;   // < 512*LDK exactly
        int j = idx / LDK;
        int k = idx - j * LDK;
        int col   = (j < EMB) ? j : (j - EMB);
        int baseE = (j < EMB) ? 256 : 778;
        int baseD = (j < EMB) ? 512 : 1034;
        float v = 0.0f;
        if (k < EMB)            v = W1[(long long)(baseE + k) * EMB + col];
        else if (k < EMB + DDE) v = W1[(long long)(baseD + (k - EMB)) * EMB + col];
        wT[idx] = f2bf(v);
    } else {
        // Prb[r][j] = bf16( b1[j] + q@W1[0:256,j] + rel[r]@W1[522:778,j] )
        int r = b - SC1 - COPY - WT_BLK;
        int j = threadIdx.x;
        float acc = b1[j];
        for (int k = 0; k < EMB; ++k)
            acc = fmaf(qv[k], W1[(long long)k * EMB + j], acc);
        const float* relr = rel + (long long)r * EMB;
        for (int k = 0; k < EMB; ++k)
            acc = fmaf(relr[k], W1[(long long)(522 + k) * EMB + j], acc);
        Prb[(long long)r * EMB + j] = f2bf(acc);
    }
}

// ---------------- scatter round 2 (pure; unpacks round-1 words inline) ----------------

__global__ void k_r2(const int* __restrict__ h_id, const int* __restrict__ t_id,
                     const unsigned long long* __restrict__ fwd,
                     const unsigned long long* __restrict__ rev,
                     unsigned long long* __restrict__ s2,
                     unsigned long long* __restrict__ sr2, int E) {
    int e = blockIdx.x * blockDim.x + threadIdx.x;
    if (e >= E) return;
    int h = h_id[e], t = t_id[e];
    float2 dh = unpack2(fwd[h]);   // d1n[h]
    float2 rt = unpack2(rev[t]);   // r1n[t]
    atomicAdd(&s2[t], pack2(dh.x, dh.y));
    atomicAdd(&sr2[h], pack2(rt.x, rt.y));
}

// ---------------- fused norm2 + h_e tail (cols 256..287) ----------------

__global__ void k_tail(const float2* __restrict__ topic,
                       const unsigned long long* __restrict__ fwd,
                       const unsigned long long* __restrict__ rev,
                       const unsigned long long* __restrict__ s2,
                       const unsigned long long* __restrict__ sr2,
                       ushort4* __restrict__ he4, int N, int Mpad) {
    int idx = blockIdx.x * blockDim.x + threadIdx.x;
    if (idx >= Mpad * 8) return;
    int n = idx >> 3, j = idx & 7;
    float4 v = make_float4(0.f, 0.f, 0.f, 0.f);
    if (n < N && j < 3) {
        if (j == 0) {
            float2 a = topic[n];
            float2 b = unpack2(fwd[n]);                       // d1
            v = make_float4(a.x, a.y, b.x, b.y);
        } else if (j == 1) {
            float df = fmaxf((float)(unsigned int)(fwd[n] & 0x3FFULL), 1.0f);
            float2 a = unpack2d(s2[n], df);                   // d2
            float2 b = unpack2(rev[n]);                       // r1
            v = make_float4(a.x, a.y, b.x, b.y);
        } else {
            float dr = fmaxf((float)(unsigned int)(rev[n] & 0x3FFULL), 1.0f);
            float2 a = unpack2d(sr2[n], dr);                  // r2
            v = make_float4(a.x, a.y, 0.f, 0.f);
        }
    }
    he4[(size_t)n * (LDK / 4) + 64 + j] = make_ushort4(f2bf(v.x), f2bf(v.y), f2bf(v.z), f2bf(v.w));
}

// ---------------- MFMA GEMM: P[M,512] = he[M,288] @ wT^T ----------------
// 128x256 tile, 8 waves (2x4), each wave 64x64 = 4x4 MFMA 16x16x32 frags.
__global__ __launch_bounds__(512) void k_gemm(const unsigned short* __restrict__ he,
                                              const unsigned short* __restrict__ wT,
                                              unsigned short* __restrict__ Ph,
                                              unsigned short* __restrict__ Pt) {
    __shared__ __align__(16) unsigned short lA[128 * 32];
    __shared__ __align__(16) unsigned short lB[256 * 32];
    const int t = threadIdx.x;      // 0..511
    const int lane = t & 63;
    const int w = t >> 6;           // 0..7
    const int br = blockIdx.x >> 1;
    const int bc = blockIdx.x & 1;  // 0 -> Ph cols, 1 -> Pt cols
    const int wr = w >> 2;          // 0..1
    const int wc = w & 3;           // 0..3

    f32x4 acc[4][4];
#pragma unroll
    for (int r = 0; r < 4; ++r)
#pragma unroll
        for (int c = 0; c < 4; ++c)
            acc[r][c] = (f32x4){0.f, 0.f, 0.f, 0.f};

    const char* baseA = (const char*)he + (size_t)(br * 128) * (LDK * 2);
    const char* baseB = (const char*)wT + (size_t)(bc * 256) * (LDK * 2);

    const int rowX = t >> 2;            // 0..127
    const int colb = (t & 3) * 16;      // 0/16/32/48 within the 64B K-slice

    for (int k0 = 0; k0 < LDK; k0 += 32) {
        __syncthreads();
        {
            const char* srcA  = baseA + (size_t)rowX * (LDK * 2) + k0 * 2 + colb;
            const char* srcB0 = baseB + (size_t)rowX * (LDK * 2) + k0 * 2 + colb;
            const char* srcB1 = baseB + (size_t)(rowX + 128) * (LDK * 2) + k0 * 2 + colb;
            __builtin_amdgcn_global_load_lds((const __attribute__((address_space(1))) void*)srcA,
                                             (__attribute__((address_space(3))) void*)((char*)lA + t * 16), 16, 0, 0);
            __builtin_amdgcn_global_load_lds((const __attribute__((address_space(1))) void*)srcB0,
                                             (__attribute__((address_space(3))) void*)((char*)lB + t * 16), 16, 0, 0);
            __builtin_amdgcn_global_load_lds((const __attribute__((address_space(1))) void*)srcB1,
                                             (__attribute__((address_space(3))) void*)((char*)lB + 8192 + t * 16), 16, 0, 0);
        }
        __syncthreads();

        short8 af[4], bfr[4];
#pragma unroll
        for (int r = 0; r < 4; ++r) {
            int arow = wr * 64 + r * 16 + (lane & 15);
            af[r] = *(const short8*)(lA + arow * 32 + (lane >> 4) * 8);
        }
#pragma unroll
        for (int c = 0; c < 4; ++c) {
            int brow = wc * 64 + c * 16 + (lane & 15);
            bfr[c] = *(const short8*)(lB + brow * 32 + (lane >> 4) * 8);
        }
#pragma unroll
        for (int r = 0; r < 4; ++r)
#pragma unroll
            for (int c = 0; c < 4; ++c)
                acc[r][c] = __builtin_amdgcn_mfma_f32_16x16x32_bf16(af[r], bfr[c], acc[r][c], 0, 0, 0);
    }

    // epilogue: C/D layout col=lane&15, row=(lane>>4)*4+i  (store bf16)
    unsigned short* Pout = bc ? Pt : Ph;
    const int nbase = wc * 64;
    const int mbase = br * 128 + wr * 64 + (lane >> 4) * 4;
#pragma unroll
    for (int r = 0; r < 4; ++r) {
#pragma unroll
        for (int c = 0; c < 4; ++c) {
            int n = nbase + c * 16 + (lane & 15);
#pragma unroll
            for (int i = 0; i < 4; ++i) {
                int m = mbase + r * 16 + i;
                Pout[(size_t)m * EMB + n] = f2bf(acc[r][c][i]);
            }
        }
    }
}

// ---------------- per-edge epilogue ----------------
// half-wave per edge: 32 lanes x 8 cols (short8, 16B) = 256 cols.
// Each wave: 2 edges per gather round, 2 rounds in flight (4 edges/iter).
__device__ __forceinline__ short8 ntload(const unsigned short* p) {
    union { int4v i; short8 s; } u;
    u.i = __builtin_nontemporal_load((const int4v*)p);
    return u.s;
}

__global__ __launch_bounds__(256) void k_edge(
    const int* __restrict__ h_id, const int* __restrict__ r_id, const int* __restrict__ t_id,
    const unsigned short* __restrict__ Ph, const unsigned short* __restrict__ Pt,
    const unsigned short* __restrict__ Prb, const float* __restrict__ W2,
    const float* __restrict__ b2, float* __restrict__ out, int E) {
    const int lane = threadIdx.x & 63;
    const int half = lane >> 5;
    const int l32  = lane & 31;
    const int gw = (blockIdx.x * blockDim.x + threadIdx.x) >> 6;
    const int nw = (gridDim.x * blockDim.x) >> 6;
    const int lo = l32 * 8;
    float w2v[8];
    *(float4*)&w2v[0] = *(const float4*)(W2 + lo);
    *(float4*)&w2v[4] = *(const float4*)(W2 + lo + 4);
    const float bb = b2[0];

    for (int e0 = gw * 4; e0 < E; e0 += nw * 4) {
        short8 ph[2], pt[2], pr[2];
        int ev[2];
#pragma unroll
        for (int p = 0; p < 2; ++p) {
            int e = e0 + 2 * p + half;
            ev[p] = e;
            int ec = (e < E) ? e : 0;
            int h = h_id[ec], r = r_id[ec], t = t_id[ec];
            ph[p] = ntload(Ph + (size_t)h * EMB + lo);
            pt[p] = ntload(Pt + (size_t)t * EMB + lo);
            pr[p] = *(const short8*)(Prb + (size_t)r * EMB + lo);
        }
#pragma unroll
        for (int p = 0; p < 2; ++p) {
            float acc = 0.f;
#pragma unroll
            for (int j = 0; j < 8; ++j) {
                float v = bf2f((unsigned short)pr[p][j]) + bf2f((unsigned short)ph[p][j])
                        + bf2f((unsigned short)pt[p][j]);
                acc += fmaxf(v, 0.f) * w2v[j];
            }
#pragma unroll
            for (int m = 16; m >= 1; m >>= 1) acc += __shfl_xor(acc, m, 64);
            if (l32 == 0 && ev[p] < E) out[ev[p]] = acc + bb;
        }
    }
}

// ---------------- host launch ----------------

extern "C" void kernel_launch(void* const* d_in, const int* in_sizes, int n_in,
                              void* d_out, int out_size, void* d_ws, size_t ws_size,
                              hipStream_t stream) {
    const int*   h_id    = (const int*)d_in[0];
    const int*   r_id    = (const int*)d_in[1];
    const int*   t_id    = (const int*)d_in[2];
    const float* q       = (const float*)d_in[3];
    const float* entity  = (const float*)d_in[4];
    const float* rel     = (const float*)d_in[6];
    const float* topic   = (const float*)d_in[7];
    const float* nontext = (const float*)d_in[8];
    const float* W1      = (const float*)d_in[9];
    const float* b1      = (const float*)d_in[10];
    const float* W2      = (const float*)d_in[11];
    const float* b2      = (const float*)d_in[12];

    const int E      = in_sizes[0];
    const int n_text = in_sizes[4] / EMB;   // 100000
    const int N      = in_sizes[7] / 2;     // 110000
    const int R      = in_sizes[6] / EMB;   // 500
    const int Mpad   = (N + 127) & ~127;    // 110080

    char* p = (char*)d_ws;
    auto alloc = [&](size_t bytes) {
        char* r = p;
        p += (bytes + 255) & ~(size_t)255;
        return r;
    };
    unsigned long long* fwd = (unsigned long long*)alloc((size_t)Mpad * 8);
    unsigned long long* rev = (unsigned long long*)alloc((size_t)Mpad * 8);
    unsigned long long* s2  = (unsigned long long*)alloc((size_t)Mpad * 8);
    unsigned long long* sr2 = (unsigned long long*)alloc((size_t)Mpad * 8);
    size_t zero_bytes = (size_t)(p - (char*)d_ws);
    unsigned short* he  = (unsigned short*)alloc((size_t)Mpad * LDK * 2);
    unsigned short* wT  = (unsigned short*)alloc((size_t)512 * LDK * 2);
    unsigned short* Prb = (unsigned short*)alloc((size_t)R * EMB * 2);
    unsigned short* Ph  = (unsigned short*)alloc((size_t)Mpad * EMB * 2);
    unsigned short* Pt  = (unsigned short*)alloc((size_t)Mpad * EMB * 2);

    hipMemsetAsync(d_ws, 0, zero_bytes, stream);

    const int T = 256;
    const int SC1 = (E + T - 1) / T;            // 1954
    const int COPY = Mpad / 4;                  // Mpad*64/256
    const int WT_BLK = (512 * LDK) / T;         // 576

    k_r1_fused<<<SC1 + COPY + WT_BLK + R, T, 0, stream>>>(
        h_id, t_id, (const float2*)topic, fwd, rev, E, SC1, COPY, WT_BLK,
        (const float4*)entity, (const float4*)nontext, (ushort4*)he, n_text, N,
        W1, wT, q, rel, b1, Prb);
    k_r2<<<SC1, T, 0, stream>>>(h_id, t_id, fwd, rev, s2, sr2, E);
    k_tail<<<(Mpad * 8 + T - 1) / T, T, 0, stream>>>(
        (const float2*)topic, fwd, rev, s2, sr2, (ushort4*)he, N, Mpad);

    k_gemm<<<(Mpad / 128) * 2, 512, 0, stream>>>(he, wT, Ph, Pt);

    k_edge<<<4096, T, 0, stream>>>(h_id, r_id, t_id, Ph, Pt, Prb, W2, b2, (float*)d_out, E);
}

// Round 6
// 312.882 us; speedup vs baseline: 1.0001x; 1.0001x over previous
//
#include <hip/hip_runtime.h>
#include <stdint.h>

#define EMB 256
#define LDK 288   // padded K for h_e / wT (266 -> 288, multiple of 32)
#define DDE 10

typedef __attribute__((ext_vector_type(8))) short short8;
typedef __attribute__((ext_vector_type(4))) float f32x4;
typedef __attribute__((ext_vector_type(4))) int int4v;

__device__ __forceinline__ unsigned short f2bf(float f) {
    union { float f; unsigned int u; } v; v.f = f;
    unsigned int u = v.u;
    unsigned int r = (u + 0x7FFFu + ((u >> 16) & 1u)) >> 16;  // RNE
    return (unsigned short)r;
}
__device__ __forceinline__ float bf2f(unsigned short b) {
    union { unsigned int u; float f; } v; v.u = ((unsigned int)b) << 16;
    return v.f;
}

// ---- fixed-point packed scatter ----
// u64 fields: s0 in [36,62), s1 in [10,36), deg in [0,10). values in [0,1),
// scaled 2^20; deg <= 1023, field sums stay < 2^26 -> no cross-field carry.
#define FPSCALE 1048576.0f
#define FPINV   (1.0f / 1048576.0f)

__device__ __forceinline__ unsigned long long pack2(float a, float b) {
    unsigned int ua = (unsigned int)(a * FPSCALE);
    unsigned int ub = (unsigned int)(b * FPSCALE);
    return ((unsigned long long)ua << 36) | ((unsigned long long)ub << 10);
}
__device__ __forceinline__ float2 unpack2(unsigned long long v) {
    float d = fmaxf((float)(unsigned int)(v & 0x3FFULL), 1.0f);
    return make_float2((float)((v >> 36) & 0x3FFFFFFULL) * FPINV / d,
                       (float)((v >> 10) & 0x3FFFFFFULL) * FPINV / d);
}
__device__ __forceinline__ float2 unpack2d(unsigned long long v, float d) {
    return make_float2((float)((v >> 36) & 0x3FFFFFFULL) * FPINV / d,
                       (float)((v >> 10) & 0x3FFFFFFULL) * FPINV / d);
}

// ---------------- mega kernel 1: scatter r1 (interleaved) + he copy + wT + Pr ----------------
// Block roles are Bresenham-interleaved so latency-bound scatter waves and
// BW-bound copy waves are co-resident (sequential ranges serialized: 122us, r5).

__global__ void k_r1_fused(const int* __restrict__ h_id, const int* __restrict__ t_id,
                           const float2* __restrict__ topic,
                           unsigned long long* __restrict__ fwd,
                           unsigned long long* __restrict__ rev, int E, int SC1, int COPY, int WT_BLK,
                           int TOTAL,
                           const float4* __restrict__ entity, const float4* __restrict__ nontext,
                           ushort4* __restrict__ he4, int n_text, int N,
                           const float* __restrict__ W1, unsigned short* __restrict__ wT,
                           const float* __restrict__ qv, const float* __restrict__ rel,
                           const float* __restrict__ b1, unsigned short* __restrict__ Prb) {
    const int b = blockIdx.x;
    const int sc_before = (int)(((long long)b * SC1) / TOTAL);
    const int is_scatter = (int)(((long long)(b + 1) * SC1) / TOTAL) != sc_before;
    if (is_scatter) {
        int e = sc_before * 256 + threadIdx.x;
        if (e >= E) return;
        int h = h_id[e], t = t_id[e];
        float2 th = topic[h];
        float2 tt = topic[t];
        atomicAdd(&fwd[t], pack2(th.x, th.y) | 1ULL);
        atomicAdd(&rev[h], pack2(tt.x, tt.y) | 1ULL);
        return;
    }
    const int o = b - sc_before;
    if (o < COPY) {
        // h_e columns 0..255 (64 float4 chunks per row)
        int idx = o * 256 + threadIdx.x;   // < Mpad*64 exactly
        int n = idx >> 6, q = idx & 63;
        float4 v = make_float4(0.f, 0.f, 0.f, 0.f);
        if (n < N) v = (n < n_text) ? entity[(size_t)n * 64 + q] : nontext[q];
        he4[(size_t)n * (LDK / 4) + q] = make_ushort4(f2bf(v.x), f2bf(v.y), f2bf(v.z), f2bf(v.w));
    } else if (o < COPY + WT_BLK) {
        // wT[j][k]: j<256 -> col j of W1 rows 256..521; j>=256 -> col j-256 rows 778..1043
        int idx = (o - COPY) * 256 + threadIdx.x;   // < 512*LDK exactly
        int j = idx / LDK;
        int k = idx - j * LDK;
        int col   = (j < EMB) ? j : (j - EMB);
        int baseE = (j < EMB) ? 256 : 778;
        int baseD = (j < EMB) ? 512 : 1034;
        float v = 0.0f;
        if (k < EMB)            v = W1[(long long)(baseE + k) * EMB + col];
        else if (k < EMB + DDE) v = W1[(long long)(baseD + (k - EMB)) * EMB + col];
        wT[idx] = f2bf(v);
    } else {
        // Prb[r][j] = bf16( b1[j] + q@W1[0:256,j] + rel[r]@W1[522:778,j] )
        int r = o - COPY - WT_BLK;
        int j = threadIdx.x;
        float acc = b1[j];
        for (int k = 0; k < EMB; ++k)
            acc = fmaf(qv[k], W1[(long long)k * EMB + j], acc);
        const float* relr = rel + (long long)r * EMB;
        for (int k = 0; k < EMB; ++k)
            acc = fmaf(relr[k], W1[(long long)(522 + k) * EMB + j], acc);
        Prb[(long long)r * EMB + j] = f2bf(acc);
    }
}

// ---------------- scatter round 2 (pure; unpacks round-1 words inline) ----------------

__global__ void k_r2(const int* __restrict__ h_id, const int* __restrict__ t_id,
                     const unsigned long long* __restrict__ fwd,
                     const unsigned long long* __restrict__ rev,
                     unsigned long long* __restrict__ s2,
                     unsigned long long* __restrict__ sr2, int E) {
    int e = blockIdx.x * blockDim.x + threadIdx.x;
    if (e >= E) return;
    int h = h_id[e], t = t_id[e];
    float2 dh = unpack2(fwd[h]);   // d1n[h]
    float2 rt = unpack2(rev[t]);   // r1n[t]
    atomicAdd(&s2[t], pack2(dh.x, dh.y));
    atomicAdd(&sr2[h], pack2(rt.x, rt.y));
}

// ---------------- fused norm2 + h_e tail (cols 256..287) ----------------

__global__ void k_tail(const float2* __restrict__ topic,
                       const unsigned long long* __restrict__ fwd,
                       const unsigned long long* __restrict__ rev,
                       const unsigned long long* __restrict__ s2,
                       const unsigned long long* __restrict__ sr2,
                       ushort4* __restrict__ he4, int N, int Mpad) {
    int idx = blockIdx.x * blockDim.x + threadIdx.x;
    if (idx >= Mpad * 8) return;
    int n = idx >> 3, j = idx & 7;
    float4 v = make_float4(0.f, 0.f, 0.f, 0.f);
    if (n < N && j < 3) {
        if (j == 0) {
            float2 a = topic[n];
            float2 b = unpack2(fwd[n]);                       // d1
            v = make_float4(a.x, a.y, b.x, b.y);
        } else if (j == 1) {
            float df = fmaxf((float)(unsigned int)(fwd[n] & 0x3FFULL), 1.0f);
            float2 a = unpack2d(s2[n], df);                   // d2
            float2 b = unpack2(rev[n]);                       // r1
            v = make_float4(a.x, a.y, b.x, b.y);
        } else {
            float dr = fmaxf((float)(unsigned int)(rev[n] & 0x3FFULL), 1.0f);
            float2 a = unpack2d(sr2[n], dr);                  // r2
            v = make_float4(a.x, a.y, 0.f, 0.f);
        }
    }
    he4[(size_t)n * (LDK / 4) + 64 + j] = make_ushort4(f2bf(v.x), f2bf(v.y), f2bf(v.z), f2bf(v.w));
}

// ---------------- MFMA GEMM: P[M,512] = he[M,288] @ wT^T ----------------
// 128x256 tile, 8 waves (2x4), each wave 64x64 = 4x4 MFMA 16x16x32 frags.
// XCD-chunk swizzle: both bc halves of a br land on the same XCD -> A-tile
// read from HBM once, second read hits that XCD's L2.
__global__ __launch_bounds__(512) void k_gemm(const unsigned short* __restrict__ he,
                                              const unsigned short* __restrict__ wT,
                                              unsigned short* __restrict__ Ph,
                                              unsigned short* __restrict__ Pt) {
    __shared__ __align__(16) unsigned short lA[128 * 32];
    __shared__ __align__(16) unsigned short lB[256 * 32];
    const int t = threadIdx.x;      // 0..511
    const int lane = t & 63;
    const int w = t >> 6;           // 0..7
    const int bswz = (blockIdx.x & 7) * ((int)gridDim.x >> 3) + (blockIdx.x >> 3);
    const int br = bswz >> 1;
    const int bc = bswz & 1;        // 0 -> Ph cols, 1 -> Pt cols
    const int wr = w >> 2;          // 0..1
    const int wc = w & 3;           // 0..3

    f32x4 acc[4][4];
#pragma unroll
    for (int r = 0; r < 4; ++r)
#pragma unroll
        for (int c = 0; c < 4; ++c)
            acc[r][c] = (f32x4){0.f, 0.f, 0.f, 0.f};

    const char* baseA = (const char*)he + (size_t)(br * 128) * (LDK * 2);
    const char* baseB = (const char*)wT + (size_t)(bc * 256) * (LDK * 2);

    const int rowX = t >> 2;            // 0..127
    const int colb = (t & 3) * 16;      // 0/16/32/48 within the 64B K-slice

    for (int k0 = 0; k0 < LDK; k0 += 32) {
        __syncthreads();
        {
            const char* srcA  = baseA + (size_t)rowX * (LDK * 2) + k0 * 2 + colb;
            const char* srcB0 = baseB + (size_t)rowX * (LDK * 2) + k0 * 2 + colb;
            const char* srcB1 = baseB + (size_t)(rowX + 128) * (LDK * 2) + k0 * 2 + colb;
            __builtin_amdgcn_global_load_lds((const __attribute__((address_space(1))) void*)srcA,
                                             (__attribute__((address_space(3))) void*)((char*)lA + t * 16), 16, 0, 0);
            __builtin_amdgcn_global_load_lds((const __attribute__((address_space(1))) void*)srcB0,
                                             (__attribute__((address_space(3))) void*)((char*)lB + t * 16), 16, 0, 0);
            __builtin_amdgcn_global_load_lds((const __attribute__((address_space(1))) void*)srcB1,
                                             (__attribute__((address_space(3))) void*)((char*)lB + 8192 + t * 16), 16, 0, 0);
        }
        __syncthreads();

        short8 af[4], bfr[4];
#pragma unroll
        for (int r = 0; r < 4; ++r) {
            int arow = wr * 64 + r * 16 + (lane & 15);
            af[r] = *(const short8*)(lA + arow * 32 + (lane >> 4) * 8);
        }
#pragma unroll
        for (int c = 0; c < 4; ++c) {
            int brow = wc * 64 + c * 16 + (lane & 15);
            bfr[c] = *(const short8*)(lB + brow * 32 + (lane >> 4) * 8);
        }
#pragma unroll
        for (int r = 0; r < 4; ++r)
#pragma unroll
            for (int c = 0; c < 4; ++c)
                acc[r][c] = __builtin_amdgcn_mfma_f32_16x16x32_bf16(af[r], bfr[c], acc[r][c], 0, 0, 0);
    }

    // epilogue: C/D layout col=lane&15, row=(lane>>4)*4+i  (store bf16)
    unsigned short* Pout = bc ? Pt : Ph;
    const int nbase = wc * 64;
    const int mbase = br * 128 + wr * 64 + (lane >> 4) * 4;
#pragma unroll
    for (int r = 0; r < 4; ++r) {
#pragma unroll
        for (int c = 0; c < 4; ++c) {
            int n = nbase + c * 16 + (lane & 15);
#pragma unroll
            for (int i = 0; i < 4; ++i) {
                int m = mbase + r * 16 + i;
                Pout[(size_t)m * EMB + n] = f2bf(acc[r][c][i]);
            }
        }
    }
}

// ---------------- per-edge epilogue ----------------
// half-wave per edge: 32 lanes x 8 cols (short8, 16B) = 256 cols.
// Each wave: 2 edges per gather round, 2 rounds in flight (4 edges/iter).
__device__ __forceinline__ short8 ntload(const unsigned short* p) {
    union { int4v i; short8 s; } u;
    u.i = __builtin_nontemporal_load((const int4v*)p);
    return u.s;
}

__global__ __launch_bounds__(256) void k_edge(
    const int* __restrict__ h_id, const int* __restrict__ r_id, const int* __restrict__ t_id,
    const unsigned short* __restrict__ Ph, const unsigned short* __restrict__ Pt,
    const unsigned short* __restrict__ Prb, const float* __restrict__ W2,
    const float* __restrict__ b2, float* __restrict__ out, int E) {
    const int lane = threadIdx.x & 63;
    const int half = lane >> 5;
    const int l32  = lane & 31;
    const int gw = (blockIdx.x * blockDim.x + threadIdx.x) >> 6;
    const int nw = (gridDim.x * blockDim.x) >> 6;
    const int lo = l32 * 8;
    float w2v[8];
    *(float4*)&w2v[0] = *(const float4*)(W2 + lo);
    *(float4*)&w2v[4] = *(const float4*)(W2 + lo + 4);
    const float bb = b2[0];

    for (int e0 = gw * 4; e0 < E; e0 += nw * 4) {
        short8 ph[2], pt[2], pr[2];
        int ev[2];
#pragma unroll
        for (int p = 0; p < 2; ++p) {
            int e = e0 + 2 * p + half;
            ev[p] = e;
            int ec = (e < E) ? e : 0;
            int h = h_id[ec], r = r_id[ec], t = t_id[ec];
            ph[p] = ntload(Ph + (size_t)h * EMB + lo);
            pt[p] = ntload(Pt + (size_t)t * EMB + lo);
            pr[p] = *(const short8*)(Prb + (size_t)r * EMB + lo);
        }
#pragma unroll
        for (int p = 0; p < 2; ++p) {
            float acc = 0.f;
#pragma unroll
            for (int j = 0; j < 8; ++j) {
                float v = bf2f((unsigned short)pr[p][j]) + bf2f((unsigned short)ph[p][j])
                        + bf2f((unsigned short)pt[p][j]);
                acc += fmaxf(v, 0.f) * w2v[j];
            }
#pragma unroll
            for (int m = 16; m >= 1; m >>= 1) acc += __shfl_xor(acc, m, 64);
            if (l32 == 0 && ev[p] < E) out[ev[p]] = acc + bb;
        }
    }
}

// ---------------- host launch ----------------

extern "C" void kernel_launch(void* const* d_in, const int* in_sizes, int n_in,
                              void* d_out, int out_size, void* d_ws, size_t ws_size,
                              hipStream_t stream) {
    const int*   h_id    = (const int*)d_in[0];
    const int*   r_id    = (const int*)d_in[1];
    const int*   t_id    = (const int*)d_in[2];
    const float* q       = (const float*)d_in[3];
    const float* entity  = (const float*)d_in[4];
    const float* rel     = (const float*)d_in[6];
    const float* topic   = (const float*)d_in[7];
    const float* nontext = (const float*)d_in[8];
    const float* W1      = (const float*)d_in[9];
    const float* b1      = (const float*)d_in[10];
    const float* W2      = (const float*)d_in[11];
    const float* b2      = (const float*)d_in[12];

    const int E      = in_sizes[0];
    const int n_text = in_sizes[4] / EMB;   // 100000
    const int N      = in_sizes[7] / 2;     // 110000
    const int R      = in_sizes[6] / EMB;   // 500
    const int Mpad   = (N + 127) & ~127;    // 110080

    char* p = (char*)d_ws;
    auto alloc = [&](size_t bytes) {
        char* r = p;
        p += (bytes + 255) & ~(size_t)255;
        return r;
    };
    unsigned long long* fwd = (unsigned long long*)alloc((size_t)Mpad * 8);
    unsigned long long* rev = (unsigned long long*)alloc((size_t)Mpad * 8);
    unsigned long long* s2  = (unsigned long long*)alloc((size_t)Mpad * 8);
    unsigned long long* sr2 = (unsigned long long*)alloc((size_t)Mpad * 8);
    size_t zero_bytes = (size_t)(p - (char*)d_ws);
    unsigned short* he  = (unsigned short*)alloc((size_t)Mpad * LDK * 2);
    unsigned short* wT  = (unsigned short*)alloc((size_t)512 * LDK * 2);
    unsigned short* Prb = (unsigned short*)alloc((size_t)R * EMB * 2);
    unsigned short* Ph  = (unsigned short*)alloc((size_t)Mpad * EMB * 2);
    unsigned short* Pt  = (unsigned short*)alloc((size_t)Mpad * EMB * 2);

    hipMemsetAsync(d_ws, 0, zero_bytes, stream);

    const int T = 256;
    const int SC1 = (E + T - 1) / T;            // 1954
    const int COPY = Mpad / 4;                  // Mpad*64/256 = 27520
    const int WT_BLK = (512 * LDK) / T;         // 576
    const int TOTAL = SC1 + COPY + WT_BLK + R;  // 30550

    k_r1_fused<<<TOTAL, T, 0, stream>>>(
        h_id, t_id, (const float2*)topic, fwd, rev, E, SC1, COPY, WT_BLK, TOTAL,
        (const float4*)entity, (const float4*)nontext, (ushort4*)he, n_text, N,
        W1, wT, q, rel, b1, Prb);
    k_r2<<<SC1, T, 0, stream>>>(h_id, t_id, fwd, rev, s2, sr2, E);
    k_tail<<<(Mpad * 8 + T - 1) / T, T, 0, stream>>>(
        (const float2*)topic, fwd, rev, s2, sr2, (ushort4*)he, N, Mpad);

    k_gemm<<<(Mpad / 128) * 2, 512, 0, stream>>>(he, wT, Ph, Pt);

    k_edge<<<4096, T, 0, stream>>>(h_id, r_id, t_id, Ph, Pt, Prb, W2, b2, (float*)d_out, E);
}

// Round 7
// 304.645 us; speedup vs baseline: 1.0272x; 1.0270x over previous
//
#include <hip/hip_runtime.h>
#include <stdint.h>

#define EMB 256
#define LDKB 288  // wT K extent (266 -> 288, multiple of 32); he uses LDA=256
#define DDE 10

typedef __attribute__((ext_vector_type(8))) short short8;
typedef __attribute__((ext_vector_type(4))) float f32x4;

__device__ __forceinline__ unsigned short f2bf(float f) {
    union { float f; unsigned int u; } v; v.f = f;
    unsigned int u = v.u;
    unsigned int r = (u + 0x7FFFu + ((u >> 16) & 1u)) >> 16;  // RNE
    return (unsigned short)r;
}
__device__ __forceinline__ float bf2f(unsigned short b) {
    union { unsigned int u; float f; } v; v.u = ((unsigned int)b) << 16;
    return v.f;
}

// ---- fixed-point packed scatter ----
// u64 fields: s0 in [36,62), s1 in [10,36), deg in [0,10). values in [0,1),
// scaled 2^20; deg <= 1023, field sums stay < 2^26 -> no cross-field carry.
#define FPSCALE 1048576.0f
#define FPINV   (1.0f / 1048576.0f)

__device__ __forceinline__ unsigned long long pack2(float a, float b) {
    unsigned int ua = (unsigned int)(a * FPSCALE);
    unsigned int ub = (unsigned int)(b * FPSCALE);
    return ((unsigned long long)ua << 36) | ((unsigned long long)ub << 10);
}
__device__ __forceinline__ float2 unpack2(unsigned long long v) {
    float d = fmaxf((float)(unsigned int)(v & 0x3FFULL), 1.0f);
    return make_float2((float)((v >> 36) & 0x3FFFFFFULL) * FPINV / d,
                       (float)((v >> 10) & 0x3FFFFFFULL) * FPINV / d);
}
__device__ __forceinline__ float2 unpack2d(unsigned long long v, float d) {
    return make_float2((float)((v >> 36) & 0x3FFFFFFULL) * FPINV / d,
                       (float)((v >> 10) & 0x3FFFFFFULL) * FPINV / d);
}

// ---------------- mega kernel 1: scatter r1 (interleaved) + he copy + wT + Pr ----------------
// Block roles Bresenham-interleaved: latency-bound scatter waves co-resident
// with BW-bound copy waves (sequential ranges serialized at 122us, r5).

__global__ void k_r1_fused(const int* __restrict__ h_id, const int* __restrict__ t_id,
                           const float2* __restrict__ topic,
                           unsigned long long* __restrict__ fwd,
                           unsigned long long* __restrict__ rev, int E, int SC1, int COPY, int WT_BLK,
                           int TOTAL,
                           const float4* __restrict__ entity, const float4* __restrict__ nontext,
                           ushort4* __restrict__ he4, int n_text, int N,
                           const float* __restrict__ W1, unsigned short* __restrict__ wT,
                           const float* __restrict__ qv, const float* __restrict__ rel,
                           const float* __restrict__ b1, unsigned short* __restrict__ Prb) {
    const int b = blockIdx.x;
    const int sc_before = (int)(((long long)b * SC1) / TOTAL);
    const int is_scatter = (int)(((long long)(b + 1) * SC1) / TOTAL) != sc_before;
    if (is_scatter) {
        int e = sc_before * 256 + threadIdx.x;
        if (e >= E) return;
        int h = h_id[e], t = t_id[e];
        float2 th = topic[h];
        float2 tt = topic[t];
        atomicAdd(&fwd[t], pack2(th.x, th.y) | 1ULL);
        atomicAdd(&rev[h], pack2(tt.x, tt.y) | 1ULL);
        return;
    }
    const int o = b - sc_before;
    if (o < COPY) {
        // h_e columns 0..255 (64 float4 chunks per row), LDA = 256
        int idx = o * 256 + threadIdx.x;   // < Mpad*64 exactly
        int n = idx >> 6, q = idx & 63;
        float4 v = make_float4(0.f, 0.f, 0.f, 0.f);
        if (n < N) v = (n < n_text) ? entity[(size_t)n * 64 + q] : nontext[q];
        he4[(size_t)n * 64 + q] = make_ushort4(f2bf(v.x), f2bf(v.y), f2bf(v.z), f2bf(v.w));
    } else if (o < COPY + WT_BLK) {
        // wT[j][k]: j<256 -> col j of W1 rows 256..521; j>=256 -> col j-256 rows 778..1043
        int idx = (o - COPY) * 256 + threadIdx.x;   // < 512*LDKB exactly
        int j = idx / LDKB;
        int k = idx - j * LDKB;
        int col   = (j < EMB) ? j : (j - EMB);
        int baseE = (j < EMB) ? 256 : 778;
        int baseD = (j < EMB) ? 512 : 1034;
        float v = 0.0f;
        if (k < EMB)            v = W1[(long long)(baseE + k) * EMB + col];
        else if (k < EMB + DDE) v = W1[(long long)(baseD + (k - EMB)) * EMB + col];
        wT[idx] = f2bf(v);
    } else {
        // Prb[r][j] = bf16( b1[j] + q@W1[0:256,j] + rel[r]@W1[522:778,j] )
        int r = o - COPY - WT_BLK;
        int j = threadIdx.x;
        float acc = b1[j];
        for (int k = 0; k < EMB; ++k)
            acc = fmaf(qv[k], W1[(long long)k * EMB + j], acc);
        const float* relr = rel + (long long)r * EMB;
        for (int k = 0; k < EMB; ++k)
            acc = fmaf(relr[k], W1[(long long)(522 + k) * EMB + j], acc);
        Prb[(long long)r * EMB + j] = f2bf(acc);
    }
}

// ---------------- scatter round 2 (pure; unpacks round-1 words inline) ----------------

__global__ void k_r2(const int* __restrict__ h_id, const int* __restrict__ t_id,
                     const unsigned long long* __restrict__ fwd,
                     const unsigned long long* __restrict__ rev,
                     unsigned long long* __restrict__ s2,
                     unsigned long long* __restrict__ sr2, int E) {
    int e = blockIdx.x * blockDim.x + threadIdx.x;
    if (e >= E) return;
    int h = h_id[e], t = t_id[e];
    float2 dh = unpack2(fwd[h]);   // d1n[h]
    float2 rt = unpack2(rev[t]);   // r1n[t]
    atomicAdd(&s2[t], pack2(dh.x, dh.y));
    atomicAdd(&sr2[h], pack2(rt.x, rt.y));
}

// ---------------- MFMA GEMM: P[M,512] = [he | dde][M,288] @ wT^T ----------------
// 128x256 tile, 8 waves (2x4), each wave 64x64 = 4x4 MFMA 16x16x32 frags.
// Last K-step (k0=256): A-tile DDE columns computed in-kernel from the packed
// scatter words (L2-resident) and ds_written into LDS — replaces k_tail.
// XCD-chunk swizzle keeps both bc halves of a br on one XCD (A-tile L2 reuse).
__global__ __launch_bounds__(512) void k_gemm(const unsigned short* __restrict__ he,
                                              const unsigned short* __restrict__ wT,
                                              unsigned short* __restrict__ Ph,
                                              unsigned short* __restrict__ Pt,
                                              const float2* __restrict__ topic,
                                              const unsigned long long* __restrict__ fwd,
                                              const unsigned long long* __restrict__ rev,
                                              const unsigned long long* __restrict__ s2,
                                              const unsigned long long* __restrict__ sr2,
                                              int N) {
    __shared__ __align__(16) unsigned short lA[128 * 32];
    __shared__ __align__(16) unsigned short lB[256 * 32];
    const int t = threadIdx.x;      // 0..511
    const int lane = t & 63;
    const int w = t >> 6;           // 0..7
    const int bswz = (blockIdx.x & 7) * ((int)gridDim.x >> 3) + (blockIdx.x >> 3);
    const int br = bswz >> 1;
    const int bc = bswz & 1;        // 0 -> Ph cols, 1 -> Pt cols
    const int wr = w >> 2;          // 0..1
    const int wc = w & 3;           // 0..3

    f32x4 acc[4][4];
#pragma unroll
    for (int r = 0; r < 4; ++r)
#pragma unroll
        for (int c = 0; c < 4; ++c)
            acc[r][c] = (f32x4){0.f, 0.f, 0.f, 0.f};

    const char* baseA = (const char*)he + (size_t)(br * 128) * (EMB * 2);
    const char* baseB = (const char*)wT + (size_t)(bc * 256) * (LDKB * 2);

    const int rowX = t >> 2;            // 0..127
    const int colb = (t & 3) * 16;      // 0/16/32/48 within the 64B K-slice

    for (int k0 = 0; k0 < LDKB; k0 += 32) {
        __syncthreads();
        if (k0 < EMB) {
            const char* srcA = baseA + (size_t)rowX * (EMB * 2) + k0 * 2 + colb;
            __builtin_amdgcn_global_load_lds((const __attribute__((address_space(1))) void*)srcA,
                                             (__attribute__((address_space(3))) void*)((char*)lA + t * 16), 16, 0, 0);
        } else {
            // compute DDE cols 256..287 for row n = br*128 + rowX
            const int n = br * 128 + rowX;
            short8 hv = (short8){0, 0, 0, 0, 0, 0, 0, 0};
            const int q4 = t & 3;
            if (n < N) {
                if (q4 == 0) {
                    float2 tp = topic[n];
                    unsigned long long f = fwd[n];
                    unsigned long long r = rev[n];
                    float df = fmaxf((float)(unsigned int)(f & 0x3FFULL), 1.0f);
                    float2 d1 = unpack2d(f, df);
                    float2 d2 = unpack2d(s2[n], df);
                    float2 r1 = unpack2(r);
                    hv[0] = (short)f2bf(tp.x); hv[1] = (short)f2bf(tp.y);
                    hv[2] = (short)f2bf(d1.x); hv[3] = (short)f2bf(d1.y);
                    hv[4] = (short)f2bf(d2.x); hv[5] = (short)f2bf(d2.y);
                    hv[6] = (short)f2bf(r1.x); hv[7] = (short)f2bf(r1.y);
                } else if (q4 == 1) {
                    unsigned long long r = rev[n];
                    float dr = fmaxf((float)(unsigned int)(r & 0x3FFULL), 1.0f);
                    float2 r2 = unpack2d(sr2[n], dr);
                    hv[0] = (short)f2bf(r2.x); hv[1] = (short)f2bf(r2.y);
                }
            }
            *(short8*)((char*)lA + rowX * 64 + q4 * 16) = hv;
        }
        {
            const char* srcB0 = baseB + (size_t)rowX * (LDKB * 2) + k0 * 2 + colb;
            const char* srcB1 = baseB + (size_t)(rowX + 128) * (LDKB * 2) + k0 * 2 + colb;
            __builtin_amdgcn_global_load_lds((const __attribute__((address_space(1))) void*)srcB0,
                                             (__attribute__((address_space(3))) void*)((char*)lB + t * 16), 16, 0, 0);
            __builtin_amdgcn_global_load_lds((const __attribute__((address_space(1))) void*)srcB1,
                                             (__attribute__((address_space(3))) void*)((char*)lB + 8192 + t * 16), 16, 0, 0);
        }
        __syncthreads();

        short8 af[4], bfr[4];
#pragma unroll
        for (int r = 0; r < 4; ++r) {
            int arow = wr * 64 + r * 16 + (lane & 15);
            af[r] = *(const short8*)(lA + arow * 32 + (lane >> 4) * 8);
        }
#pragma unroll
        for (int c = 0; c < 4; ++c) {
            int brow = wc * 64 + c * 16 + (lane & 15);
            bfr[c] = *(const short8*)(lB + brow * 32 + (lane >> 4) * 8);
        }
#pragma unroll
        for (int r = 0; r < 4; ++r)
#pragma unroll
            for (int c = 0; c < 4; ++c)
                acc[r][c] = __builtin_amdgcn_mfma_f32_16x16x32_bf16(af[r], bfr[c], acc[r][c], 0, 0, 0);
    }

    // epilogue: C/D layout col=lane&15, row=(lane>>4)*4+i  (store bf16)
    unsigned short* Pout = bc ? Pt : Ph;
    const int nbase = wc * 64;
    const int mbase = br * 128 + wr * 64 + (lane >> 4) * 4;
#pragma unroll
    for (int r = 0; r < 4; ++r) {
#pragma unroll
        for (int c = 0; c < 4; ++c) {
            int n = nbase + c * 16 + (lane & 15);
#pragma unroll
            for (int i = 0; i < 4; ++i) {
                int m = mbase + r * 16 + i;
                Pout[(size_t)m * EMB + n] = f2bf(acc[r][c][i]);
            }
        }
    }
}

// ---------------- per-edge epilogue (round-3 proven form) ----------------
// one wave per edge: lane l covers cols 4l..4l+3 (ushort4, 8B) -> 512B/load.
__global__ __launch_bounds__(256) void k_edge(
    const int* __restrict__ h_id, const int* __restrict__ r_id, const int* __restrict__ t_id,
    const unsigned short* __restrict__ Ph, const unsigned short* __restrict__ Pt,
    const unsigned short* __restrict__ Prb, const float* __restrict__ W2,
    const float* __restrict__ b2, float* __restrict__ out, int E) {
    int lane = threadIdx.x & 63;
    int gw = (blockIdx.x * blockDim.x + threadIdx.x) >> 6;
    int nw = (gridDim.x * blockDim.x) >> 6;
    float4 w2 = *(const float4*)(W2 + 4 * lane);
    float bb = b2[0];
    const int lo = 4 * lane;
    for (int e = gw; e < E; e += nw) {
        int h = h_id[e], r = r_id[e], t = t_id[e];
        ushort4 ph = *(const ushort4*)(Ph + (size_t)h * EMB + lo);
        ushort4 pt = *(const ushort4*)(Pt + (size_t)t * EMB + lo);
        ushort4 pr = *(const ushort4*)(Prb + (size_t)r * EMB + lo);
        float v, acc;
        v = bf2f(pr.x) + bf2f(ph.x) + bf2f(pt.x); acc  = fmaxf(v, 0.f) * w2.x;
        v = bf2f(pr.y) + bf2f(ph.y) + bf2f(pt.y); acc += fmaxf(v, 0.f) * w2.y;
        v = bf2f(pr.z) + bf2f(ph.z) + bf2f(pt.z); acc += fmaxf(v, 0.f) * w2.z;
        v = bf2f(pr.w) + bf2f(ph.w) + bf2f(pt.w); acc += fmaxf(v, 0.f) * w2.w;
#pragma unroll
        for (int m = 32; m >= 1; m >>= 1) acc += __shfl_xor(acc, m, 64);
        if (lane == 0) out[e] = acc + bb;
    }
}

// ---------------- host launch ----------------

extern "C" void kernel_launch(void* const* d_in, const int* in_sizes, int n_in,
                              void* d_out, int out_size, void* d_ws, size_t ws_size,
                              hipStream_t stream) {
    const int*   h_id    = (const int*)d_in[0];
    const int*   r_id    = (const int*)d_in[1];
    const int*   t_id    = (const int*)d_in[2];
    const float* q       = (const float*)d_in[3];
    const float* entity  = (const float*)d_in[4];
    const float* rel     = (const float*)d_in[6];
    const float* topic   = (const float*)d_in[7];
    const float* nontext = (const float*)d_in[8];
    const float* W1      = (const float*)d_in[9];
    const float* b1      = (const float*)d_in[10];
    const float* W2      = (const float*)d_in[11];
    const float* b2      = (const float*)d_in[12];

    const int E      = in_sizes[0];
    const int n_text = in_sizes[4] / EMB;   // 100000
    const int N      = in_sizes[7] / 2;     // 110000
    const int R      = in_sizes[6] / EMB;   // 500
    const int Mpad   = (N + 127) & ~127;    // 110080

    char* p = (char*)d_ws;
    auto alloc = [&](size_t bytes) {
        char* r = p;
        p += (bytes + 255) & ~(size_t)255;
        return r;
    };
    unsigned long long* fwd = (unsigned long long*)alloc((size_t)Mpad * 8);
    unsigned long long* rev = (unsigned long long*)alloc((size_t)Mpad * 8);
    unsigned long long* s2  = (unsigned long long*)alloc((size_t)Mpad * 8);
    unsigned long long* sr2 = (unsigned long long*)alloc((size_t)Mpad * 8);
    size_t zero_bytes = (size_t)(p - (char*)d_ws);
    unsigned short* he  = (unsigned short*)alloc((size_t)Mpad * EMB * 2);
    unsigned short* wT  = (unsigned short*)alloc((size_t)512 * LDKB * 2);
    unsigned short* Prb = (unsigned short*)alloc((size_t)R * EMB * 2);
    unsigned short* Ph  = (unsigned short*)alloc((size_t)Mpad * EMB * 2);
    unsigned short* Pt  = (unsigned short*)alloc((size_t)Mpad * EMB * 2);

    hipMemsetAsync(d_ws, 0, zero_bytes, stream);

    const int T = 256;
    const int SC1 = (E + T - 1) / T;            // 1954
    const int COPY = Mpad / 4;                  // Mpad*64/256 = 27520
    const int WT_BLK = (512 * LDKB) / T;        // 576
    const int TOTAL = SC1 + COPY + WT_BLK + R;

    k_r1_fused<<<TOTAL, T, 0, stream>>>(
        h_id, t_id, (const float2*)topic, fwd, rev, E, SC1, COPY, WT_BLK, TOTAL,
        (const float4*)entity, (const float4*)nontext, (ushort4*)he, n_text, N,
        W1, wT, q, rel, b1, Prb);
    k_r2<<<SC1, T, 0, stream>>>(h_id, t_id, fwd, rev, s2, sr2, E);

    k_gemm<<<(Mpad / 128) * 2, 512, 0, stream>>>(he, wT, Ph, Pt,
                                                 (const float2*)topic, fwd, rev, s2, sr2, N);

    k_edge<<<8192, T, 0, stream>>>(h_id, r_id, t_id, Ph, Pt, Prb, W2, b2, (float*)d_out, E);
}

// Round 8
// 295.874 us; speedup vs baseline: 1.0576x; 1.0296x over previous
//
#include <hip/hip_runtime.h>
#include <stdint.h>

#define EMB 256
#define LDKB 288  // wT K extent (266 -> 288, multiple of 32); he uses LDA=256
#define DDE 10

typedef __attribute__((ext_vector_type(8))) short short8;
typedef __attribute__((ext_vector_type(4))) float f32x4;

__device__ __forceinline__ unsigned short f2bf(float f) {
    union { float f; unsigned int u; } v; v.f = f;
    unsigned int u = v.u;
    unsigned int r = (u + 0x7FFFu + ((u >> 16) & 1u)) >> 16;  // RNE
    return (unsigned short)r;
}
__device__ __forceinline__ float bf2f(unsigned short b) {
    union { unsigned int u; float f; } v; v.u = ((unsigned int)b) << 16;
    return v.f;
}

// ---- fixed-point packed scatter ----
// u64 fields: s0 in [36,62), s1 in [10,36), deg in [0,10). values in [0,1),
// scaled 2^20; deg <= 1023, field sums stay < 2^26 -> no cross-field carry.
#define FPSCALE 1048576.0f
#define FPINV   (1.0f / 1048576.0f)

__device__ __forceinline__ unsigned long long pack2(float a, float b) {
    unsigned int ua = (unsigned int)(a * FPSCALE);
    unsigned int ub = (unsigned int)(b * FPSCALE);
    return ((unsigned long long)ua << 36) | ((unsigned long long)ub << 10);
}
__device__ __forceinline__ float2 unpack2(unsigned long long v) {
    float d = fmaxf((float)(unsigned int)(v & 0x3FFULL), 1.0f);
    return make_float2((float)((v >> 36) & 0x3FFFFFFULL) * FPINV / d,
                       (float)((v >> 10) & 0x3FFFFFFULL) * FPINV / d);
}
__device__ __forceinline__ float2 unpack2d(unsigned long long v, float d) {
    return make_float2((float)((v >> 36) & 0x3FFFFFFULL) * FPINV / d,
                       (float)((v >> 10) & 0x3FFFFFFULL) * FPINV / d);
}

// ---------------- mega kernel 1: scatter r1 (interleaved) + he copy + wT + Pr ----------------
// Block roles Bresenham-interleaved: latency-bound scatter waves co-resident
// with BW-bound copy waves (sequential ranges serialized at 122us, r5).

__global__ void k_r1_fused(const int* __restrict__ h_id, const int* __restrict__ t_id,
                           const float2* __restrict__ topic,
                           unsigned long long* __restrict__ fwd,
                           unsigned long long* __restrict__ rev, int E, int SC1, int COPY, int WT_BLK,
                           int TOTAL,
                           const float4* __restrict__ entity, const float4* __restrict__ nontext,
                           ushort4* __restrict__ he4, int n_text, int N,
                           const float* __restrict__ W1, unsigned short* __restrict__ wT,
                           const float* __restrict__ qv, const float* __restrict__ rel,
                           const float* __restrict__ b1, unsigned short* __restrict__ Prb) {
    const int b = blockIdx.x;
    const int sc_before = (int)(((long long)b * SC1) / TOTAL);
    const int is_scatter = (int)(((long long)(b + 1) * SC1) / TOTAL) != sc_before;
    if (is_scatter) {
        int e = sc_before * 256 + threadIdx.x;
        if (e >= E) return;
        int h = h_id[e], t = t_id[e];
        float2 th = topic[h];
        float2 tt = topic[t];
        atomicAdd(&fwd[t], pack2(th.x, th.y) | 1ULL);
        atomicAdd(&rev[h], pack2(tt.x, tt.y) | 1ULL);
        return;
    }
    const int o = b - sc_before;
    if (o < COPY) {
        // h_e columns 0..255 (64 float4 chunks per row), LDA = 256
        int idx = o * 256 + threadIdx.x;   // < Mpad*64 exactly
        int n = idx >> 6, q = idx & 63;
        float4 v = make_float4(0.f, 0.f, 0.f, 0.f);
        if (n < N) v = (n < n_text) ? entity[(size_t)n * 64 + q] : nontext[q];
        he4[(size_t)n * 64 + q] = make_ushort4(f2bf(v.x), f2bf(v.y), f2bf(v.z), f2bf(v.w));
    } else if (o < COPY + WT_BLK) {
        // wT[j][k]: j<256 -> col j of W1 rows 256..521; j>=256 -> col j-256 rows 778..1043
        int idx = (o - COPY) * 256 + threadIdx.x;   // < 512*LDKB exactly
        int j = idx / LDKB;
        int k = idx - j * LDKB;
        int col   = (j < EMB) ? j : (j - EMB);
        int baseE = (j < EMB) ? 256 : 778;
        int baseD = (j < EMB) ? 512 : 1034;
        float v = 0.0f;
        if (k < EMB)            v = W1[(long long)(baseE + k) * EMB + col];
        else if (k < EMB + DDE) v = W1[(long long)(baseD + (k - EMB)) * EMB + col];
        wT[idx] = f2bf(v);
    } else {
        // Prb[r][j] = bf16( b1[j] + q@W1[0:256,j] + rel[r]@W1[522:778,j] )
        int r = o - COPY - WT_BLK;
        int j = threadIdx.x;
        float acc = b1[j];
        for (int k = 0; k < EMB; ++k)
            acc = fmaf(qv[k], W1[(long long)k * EMB + j], acc);
        const float* relr = rel + (long long)r * EMB;
        for (int k = 0; k < EMB; ++k)
            acc = fmaf(relr[k], W1[(long long)(522 + k) * EMB + j], acc);
        Prb[(long long)r * EMB + j] = f2bf(acc);
    }
}

// ---------------- scatter round 2 (pure; unpacks round-1 words inline) ----------------

__global__ void k_r2(const int* __restrict__ h_id, const int* __restrict__ t_id,
                     const unsigned long long* __restrict__ fwd,
                     const unsigned long long* __restrict__ rev,
                     unsigned long long* __restrict__ s2,
                     unsigned long long* __restrict__ sr2, int E) {
    int e = blockIdx.x * blockDim.x + threadIdx.x;
    if (e >= E) return;
    int h = h_id[e], t = t_id[e];
    float2 dh = unpack2(fwd[h]);   // d1n[h]
    float2 rt = unpack2(rev[t]);   // r1n[t]
    atomicAdd(&s2[t], pack2(dh.x, dh.y));
    atomicAdd(&sr2[h], pack2(rt.x, rt.y));
}

// ---------------- MFMA GEMM: P[M,512] = [he | dde][M,288] @ wT^T ----------------
// 128x256 tile, 8 waves (2x4), 64x64/wave. DOUBLE-BUFFERED staging: stage
// K-step k+1 while computing k; __syncthreads() drains vmcnt+lgkm and
// publishes the staged tile (T3-minimum 2-phase). Last K-step's A-subtile
// (DDE cols 256..287) is computed in-kernel from the packed scatter words
// and ds_written into the staging buffer (replaces k_tail).
__global__ __launch_bounds__(512) void k_gemm(const unsigned short* __restrict__ he,
                                              const unsigned short* __restrict__ wT,
                                              unsigned short* __restrict__ Ph,
                                              unsigned short* __restrict__ Pt,
                                              const float2* __restrict__ topic,
                                              const unsigned long long* __restrict__ fwd,
                                              const unsigned long long* __restrict__ rev,
                                              const unsigned long long* __restrict__ s2,
                                              const unsigned long long* __restrict__ sr2,
                                              int N) {
    __shared__ __align__(16) unsigned short lA[2][128 * 32];
    __shared__ __align__(16) unsigned short lB[2][256 * 32];
    const int t = threadIdx.x;      // 0..511
    const int lane = t & 63;
    const int w = t >> 6;           // 0..7
    const int bswz = (blockIdx.x & 7) * ((int)gridDim.x >> 3) + (blockIdx.x >> 3);
    const int br = bswz >> 1;
    const int bc = bswz & 1;        // 0 -> Ph cols, 1 -> Pt cols
    const int wr = w >> 2;          // 0..1
    const int wc = w & 3;           // 0..3

    f32x4 acc[4][4];
#pragma unroll
    for (int r = 0; r < 4; ++r)
#pragma unroll
        for (int c = 0; c < 4; ++c)
            acc[r][c] = (f32x4){0.f, 0.f, 0.f, 0.f};

    const char* baseA = (const char*)he + (size_t)(br * 128) * (EMB * 2);
    const char* baseB = (const char*)wT + (size_t)(bc * 256) * (LDKB * 2);

    const int rowX = t >> 2;            // 0..127
    const int colb = (t & 3) * 16;      // 0/16/32/48 within the 64B K-slice

    auto stage = [&](int k0, int buf) {
        if (k0 < EMB) {
            const char* srcA = baseA + (size_t)rowX * (EMB * 2) + k0 * 2 + colb;
            __builtin_amdgcn_global_load_lds((const __attribute__((address_space(1))) void*)srcA,
                                             (__attribute__((address_space(3))) void*)((char*)lA[buf] + t * 16), 16, 0, 0);
        } else {
            // compute DDE cols 256..287 for row n = br*128 + rowX
            const int n = br * 128 + rowX;
            short8 hv = (short8){0, 0, 0, 0, 0, 0, 0, 0};
            const int q4 = t & 3;
            if (n < N) {
                if (q4 == 0) {
                    float2 tp = topic[n];
                    unsigned long long f = fwd[n];
                    unsigned long long r = rev[n];
                    float df = fmaxf((float)(unsigned int)(f & 0x3FFULL), 1.0f);
                    float2 d1 = unpack2d(f, df);
                    float2 d2 = unpack2d(s2[n], df);
                    float2 r1 = unpack2(r);
                    hv[0] = (short)f2bf(tp.x); hv[1] = (short)f2bf(tp.y);
                    hv[2] = (short)f2bf(d1.x); hv[3] = (short)f2bf(d1.y);
                    hv[4] = (short)f2bf(d2.x); hv[5] = (short)f2bf(d2.y);
                    hv[6] = (short)f2bf(r1.x); hv[7] = (short)f2bf(r1.y);
                } else if (q4 == 1) {
                    unsigned long long r = rev[n];
                    float dr = fmaxf((float)(unsigned int)(r & 0x3FFULL), 1.0f);
                    float2 r2 = unpack2d(sr2[n], dr);
                    hv[0] = (short)f2bf(r2.x); hv[1] = (short)f2bf(r2.y);
                }
            }
            *(short8*)((char*)lA[buf] + rowX * 64 + q4 * 16) = hv;
        }
        const char* srcB0 = baseB + (size_t)rowX * (LDKB * 2) + k0 * 2 + colb;
        const char* srcB1 = baseB + (size_t)(rowX + 128) * (LDKB * 2) + k0 * 2 + colb;
        __builtin_amdgcn_global_load_lds((const __attribute__((address_space(1))) void*)srcB0,
                                         (__attribute__((address_space(3))) void*)((char*)lB[buf] + t * 16), 16, 0, 0);
        __builtin_amdgcn_global_load_lds((const __attribute__((address_space(1))) void*)srcB1,
                                         (__attribute__((address_space(3))) void*)((char*)lB[buf] + 8192 + t * 16), 16, 0, 0);
    };

    const int NK = LDKB / 32;  // 9
    stage(0, 0);
    __syncthreads();           // drains vmcnt(0) before barrier (compiler-emitted)

    for (int k = 0; k < NK; ++k) {
        const int cur = k & 1;
        if (k + 1 < NK) stage((k + 1) * 32, cur ^ 1);

        short8 af[4], bfr[4];
#pragma unroll
        for (int r = 0; r < 4; ++r) {
            int arow = wr * 64 + r * 16 + (lane & 15);
            af[r] = *(const short8*)(lA[cur] + arow * 32 + (lane >> 4) * 8);
        }
#pragma unroll
        for (int c = 0; c < 4; ++c) {
            int brow = wc * 64 + c * 16 + (lane & 15);
            bfr[c] = *(const short8*)(lB[cur] + brow * 32 + (lane >> 4) * 8);
        }
#pragma unroll
        for (int r = 0; r < 4; ++r)
#pragma unroll
            for (int c = 0; c < 4; ++c)
                acc[r][c] = __builtin_amdgcn_mfma_f32_16x16x32_bf16(af[r], bfr[c], acc[r][c], 0, 0, 0);

        __syncthreads();       // publishes buf cur^1; protects buf cur for reuse
    }

    // epilogue: C/D layout col=lane&15, row=(lane>>4)*4+i  (store bf16)
    unsigned short* Pout = bc ? Pt : Ph;
    const int nbase = wc * 64;
    const int mbase = br * 128 + wr * 64 + (lane >> 4) * 4;
#pragma unroll
    for (int r = 0; r < 4; ++r) {
#pragma unroll
        for (int c = 0; c < 4; ++c) {
            int n = nbase + c * 16 + (lane & 15);
#pragma unroll
            for (int i = 0; i < 4; ++i) {
                int m = mbase + r * 16 + i;
                Pout[(size_t)m * EMB + n] = f2bf(acc[r][c][i]);
            }
        }
    }
}

// ---------------- per-edge epilogue (round-3 proven form, grid 4096) ----------------
// one wave per edge: lane l covers cols 4l..4l+3 (ushort4, 8B) -> 512B/load.
__global__ __launch_bounds__(256) void k_edge(
    const int* __restrict__ h_id, const int* __restrict__ r_id, const int* __restrict__ t_id,
    const unsigned short* __restrict__ Ph, const unsigned short* __restrict__ Pt,
    const unsigned short* __restrict__ Prb, const float* __restrict__ W2,
    const float* __restrict__ b2, float* __restrict__ out, int E) {
    int lane = threadIdx.x & 63;
    int gw = (blockIdx.x * blockDim.x + threadIdx.x) >> 6;
    int nw = (gridDim.x * blockDim.x) >> 6;
    float4 w2 = *(const float4*)(W2 + 4 * lane);
    float bb = b2[0];
    const int lo = 4 * lane;
    for (int e = gw; e < E; e += nw) {
        int h = h_id[e], r = r_id[e], t = t_id[e];
        ushort4 ph = *(const ushort4*)(Ph + (size_t)h * EMB + lo);
        ushort4 pt = *(const ushort4*)(Pt + (size_t)t * EMB + lo);
        ushort4 pr = *(const ushort4*)(Prb + (size_t)r * EMB + lo);
        float v, acc;
        v = bf2f(pr.x) + bf2f(ph.x) + bf2f(pt.x); acc  = fmaxf(v, 0.f) * w2.x;
        v = bf2f(pr.y) + bf2f(ph.y) + bf2f(pt.y); acc += fmaxf(v, 0.f) * w2.y;
        v = bf2f(pr.z) + bf2f(ph.z) + bf2f(pt.z); acc += fmaxf(v, 0.f) * w2.z;
        v = bf2f(pr.w) + bf2f(ph.w) + bf2f(pt.w); acc += fmaxf(v, 0.f) * w2.w;
#pragma unroll
        for (int m = 32; m >= 1; m >>= 1) acc += __shfl_xor(acc, m, 64);
        if (lane == 0) out[e] = acc + bb;
    }
}

// ---------------- host launch ----------------

extern "C" void kernel_launch(void* const* d_in, const int* in_sizes, int n_in,
                              void* d_out, int out_size, void* d_ws, size_t ws_size,
                              hipStream_t stream) {
    const int*   h_id    = (const int*)d_in[0];
    const int*   r_id    = (const int*)d_in[1];
    const int*   t_id    = (const int*)d_in[2];
    const float* q       = (const float*)d_in[3];
    const float* entity  = (const float*)d_in[4];
    const float* rel     = (const float*)d_in[6];
    const float* topic   = (const float*)d_in[7];
    const float* nontext = (const float*)d_in[8];
    const float* W1      = (const float*)d_in[9];
    const float* b1      = (const float*)d_in[10];
    const float* W2      = (const float*)d_in[11];
    const float* b2      = (const float*)d_in[12];

    const int E      = in_sizes[0];
    const int n_text = in_sizes[4] / EMB;   // 100000
    const int N      = in_sizes[7] / 2;     // 110000
    const int R      = in_sizes[6] / EMB;   // 500
    const int Mpad   = (N + 127) & ~127;    // 110080

    char* p = (char*)d_ws;
    auto alloc = [&](size_t bytes) {
        char* r = p;
        p += (bytes + 255) & ~(size_t)255;
        return r;
    };
    unsigned long long* fwd = (unsigned long long*)alloc((size_t)Mpad * 8);
    unsigned long long* rev = (unsigned long long*)alloc((size_t)Mpad * 8);
    unsigned long long* s2  = (unsigned long long*)alloc((size_t)Mpad * 8);
    unsigned long long* sr2 = (unsigned long long*)alloc((size_t)Mpad * 8);
    size_t zero_bytes = (size_t)(p - (char*)d_ws);
    unsigned short* he  = (unsigned short*)alloc((size_t)Mpad * EMB * 2);
    unsigned short* wT  = (unsigned short*)alloc((size_t)512 * LDKB * 2);
    unsigned short* Prb = (unsigned short*)alloc((size_t)R * EMB * 2);
    unsigned short* Ph  = (unsigned short*)alloc((size_t)Mpad * EMB * 2);
    unsigned short* Pt  = (unsigned short*)alloc((size_t)Mpad * EMB * 2);

    hipMemsetAsync(d_ws, 0, zero_bytes, stream);

    const int T = 256;
    const int SC1 = (E + T - 1) / T;            // 1954
    const int COPY = Mpad / 4;                  // Mpad*64/256 = 27520
    const int WT_BLK = (512 * LDKB) / T;        // 576
    const int TOTAL = SC1 + COPY + WT_BLK + R;

    k_r1_fused<<<TOTAL, T, 0, stream>>>(
        h_id, t_id, (const float2*)topic, fwd, rev, E, SC1, COPY, WT_BLK, TOTAL,
        (const float4*)entity, (const float4*)nontext, (ushort4*)he, n_text, N,
        W1, wT, q, rel, b1, Prb);
    k_r2<<<SC1, T, 0, stream>>>(h_id, t_id, fwd, rev, s2, sr2, E);

    k_gemm<<<(Mpad / 128) * 2, 512, 0, stream>>>(he, wT, Ph, Pt,
                                                 (const float2*)topic, fwd, rev, s2, sr2, N);

    k_edge<<<4096, T, 0, stream>>>(h_id, r_id, t_id, Ph, Pt, Prb, W2, b2, (float*)d_out, E);
}

// Round 9
// 294.133 us; speedup vs baseline: 1.0639x; 1.0059x over previous
//
#include <hip/hip_runtime.h>
#include <stdint.h>

#define EMB 256
#define LDKB 288  // wT K extent; he uses LDA=256
#define DDE 10

typedef __attribute__((ext_vector_type(8))) short short8;
typedef __attribute__((ext_vector_type(4))) float f32x4;

__device__ __forceinline__ unsigned short f2bf(float f) {
    union { float f; unsigned int u; } v; v.f = f;
    unsigned int u = v.u;
    unsigned int r = (u + 0x7FFFu + ((u >> 16) & 1u)) >> 16;  // RNE
    return (unsigned short)r;
}
__device__ __forceinline__ float bf2f(unsigned short b) {
    union { unsigned int u; float f; } v; v.u = ((unsigned int)b) << 16;
    return v.f;
}

// ---- fixed-point packed scatter: s0[36,62) s1[10,36) deg[0,10), scale 2^20 ----
#define FPSCALE 1048576.0f
#define FPINV   (1.0f / 1048576.0f)

__device__ __forceinline__ unsigned long long pack2(float a, float b) {
    unsigned int ua = (unsigned int)(a * FPSCALE);
    unsigned int ub = (unsigned int)(b * FPSCALE);
    return ((unsigned long long)ua << 36) | ((unsigned long long)ub << 10);
}
__device__ __forceinline__ float2 unpack2(unsigned long long v) {
    float d = fmaxf((float)(unsigned int)(v & 0x3FFULL), 1.0f);
    return make_float2((float)((v >> 36) & 0x3FFFFFFULL) * FPINV / d,
                       (float)((v >> 10) & 0x3FFFFFFULL) * FPINV / d);
}
__device__ __forceinline__ float2 unpack2d(unsigned long long v, float d) {
    return make_float2((float)((v >> 36) & 0x3FFFFFFULL) * FPINV / d,
                       (float)((v >> 10) & 0x3FFFFFFULL) * FPINV / d);
}

// ---------------- mega kernel 1: scatter r1 (interleaved) + he copy + wT + Pr + coef ----------------

__global__ void k_r1_fused(const int* __restrict__ h_id, const int* __restrict__ t_id,
                           const float2* __restrict__ topic,
                           unsigned long long* __restrict__ fwd,
                           unsigned long long* __restrict__ rev, int E, int SC1, int COPY, int WT_BLK,
                           int R, int TOTAL,
                           const float4* __restrict__ entity, const float4* __restrict__ nontext,
                           ushort4* __restrict__ he4, int n_text, int N,
                           const float* __restrict__ W1, unsigned short* __restrict__ wT,
                           const float* __restrict__ qv, const float* __restrict__ rel,
                           const float* __restrict__ b1, unsigned short* __restrict__ Prb,
                           float* __restrict__ cw) {
    const int b = blockIdx.x;
    const int sc_before = (int)(((long long)b * SC1) / TOTAL);
    const int is_scatter = (int)(((long long)(b + 1) * SC1) / TOTAL) != sc_before;
    if (is_scatter) {
        int e = sc_before * 256 + threadIdx.x;
        if (e >= E) return;
        int h = h_id[e], t = t_id[e];
        float2 th = topic[h];
        float2 tt = topic[t];
        atomicAdd(&fwd[t], pack2(th.x, th.y) | 1ULL);
        atomicAdd(&rev[h], pack2(tt.x, tt.y) | 1ULL);
        return;
    }
    const int o = b - sc_before;
    if (o < COPY) {
        // h_e columns 0..255 (64 float4 chunks per row), LDA = 256
        int idx = o * 256 + threadIdx.x;   // < Mpad*64 exactly
        int n = idx >> 6, q = idx & 63;
        float4 v = make_float4(0.f, 0.f, 0.f, 0.f);
        if (n < N) v = (n < n_text) ? entity[(size_t)n * 64 + q] : nontext[q];
        he4[(size_t)n * 64 + q] = make_ushort4(f2bf(v.x), f2bf(v.y), f2bf(v.z), f2bf(v.w));
    } else if (o < COPY + WT_BLK) {
        // wT[j][k]: j<256 -> col j of W1 rows 256..521; j>=256 -> col j-256 rows 778..1043
        int idx = (o - COPY) * 256 + threadIdx.x;   // < 512*LDKB exactly
        int j = idx / LDKB;
        int k = idx - j * LDKB;
        int col   = (j < EMB) ? j : (j - EMB);
        int baseE = (j < EMB) ? 256 : 778;
        int baseD = (j < EMB) ? 512 : 1034;
        float v = 0.0f;
        if (k < EMB)            v = W1[(long long)(baseE + k) * EMB + col];
        else if (k < EMB + DDE) v = W1[(long long)(baseD + (k - EMB)) * EMB + col];
        wT[idx] = f2bf(v);
    } else if (o < COPY + WT_BLK + R) {
        // Prb[r][j] = bf16( b1[j] + q@W1[0:256,j] + rel[r]@W1[522:778,j] )
        int r = o - COPY - WT_BLK;
        int j = threadIdx.x;
        float acc = b1[j];
        for (int k = 0; k < EMB; ++k)
            acc = fmaf(qv[k], W1[(long long)k * EMB + j], acc);
        const float* relr = rel + (long long)r * EMB;
        for (int k = 0; k < EMB; ++k)
            acc = fmaf(relr[k], W1[(long long)(522 + k) * EMB + j], acc);
        Prb[(long long)r * EMB + j] = f2bf(acc);
    } else {
        // cw[j][4] = fp32 {W_d2x, W_d2y, W_r2x, W_r2y} for column j (rank-4 fold)
        int idx = (o - COPY - WT_BLK - R) * 256 + threadIdx.x;   // < 2048
        if (idx < 2048) {
            int j = idx >> 2, c = idx & 3;
            int col   = (j < EMB) ? j : (j - EMB);
            int baseD = (j < EMB) ? 512 : 1034;
            int row   = baseD + ((c < 2) ? (4 + c) : (8 + (c - 2)));
            cw[idx] = W1[(long long)row * EMB + col];
        }
    }
}

// ---------------- fused GEMM + scatter r2 ----------------
// GEMM: P[M,512] = [he | topic,d1,0,r1,0][M,288] @ wT^T — depends only on r1.
// r2 scatter blocks Bresenham-interleaved: atomics run in the MFMA shadow.
// GEMM: 128x256 tile, 8 waves, double-buffered staging (r8 structure).
__global__ __launch_bounds__(512) void k_gemm_r2(const unsigned short* __restrict__ he,
                                                 const unsigned short* __restrict__ wT,
                                                 unsigned short* __restrict__ Ph,
                                                 unsigned short* __restrict__ Pt,
                                                 const float2* __restrict__ topic,
                                                 const unsigned long long* __restrict__ fwd,
                                                 const unsigned long long* __restrict__ rev,
                                                 unsigned long long* __restrict__ s2,
                                                 unsigned long long* __restrict__ sr2,
                                                 const int* __restrict__ h_id,
                                                 const int* __restrict__ t_id,
                                                 int N, int E, int GB, int TOTAL) {
    __shared__ __align__(16) unsigned short lA[2][128 * 32];
    __shared__ __align__(16) unsigned short lB[2][256 * 32];
    const int b = blockIdx.x;
    const int g_before = (int)(((long long)b * GB) / TOTAL);
    const int is_gemm = (int)(((long long)(b + 1) * GB) / TOTAL) != g_before;
    if (!is_gemm) {
        // r2 scatter role: 512 edges per block
        int e = (b - g_before) * 512 + threadIdx.x;
        if (e < E) {
            int h = h_id[e], t = t_id[e];
            float2 dh = unpack2(fwd[h]);   // d1n[h]
            float2 rt = unpack2(rev[t]);   // r1n[t]
            atomicAdd(&s2[t], pack2(dh.x, dh.y));
            atomicAdd(&sr2[h], pack2(rt.x, rt.y));
        }
        return;
    }
    const int t = threadIdx.x;      // 0..511
    const int lane = t & 63;
    const int w = t >> 6;           // 0..7
    const int o = g_before;         // gemm ordinal, 0..GB-1 (GB multiple of 8)
    const int bswz = (o & 7) * (GB >> 3) + (o >> 3);
    const int br = bswz >> 1;
    const int bc = bswz & 1;        // 0 -> Ph cols, 1 -> Pt cols
    const int wr = w >> 2;          // 0..1
    const int wc = w & 3;           // 0..3

    f32x4 acc[4][4];
#pragma unroll
    for (int r = 0; r < 4; ++r)
#pragma unroll
        for (int c = 0; c < 4; ++c)
            acc[r][c] = (f32x4){0.f, 0.f, 0.f, 0.f};

    const char* baseA = (const char*)he + (size_t)(br * 128) * (EMB * 2);
    const char* baseB = (const char*)wT + (size_t)(bc * 256) * (LDKB * 2);

    const int rowX = t >> 2;            // 0..127
    const int colb = (t & 3) * 16;      // 0/16/32/48 within the 64B K-slice

    auto stage = [&](int k0, int buf) {
        if (k0 < EMB) {
            const char* srcA = baseA + (size_t)rowX * (EMB * 2) + k0 * 2 + colb;
            __builtin_amdgcn_global_load_lds((const __attribute__((address_space(1))) void*)srcA,
                                             (__attribute__((address_space(3))) void*)((char*)lA[buf] + t * 16), 16, 0, 0);
        } else {
            // tail cols 256..287 for row n: topic(2), d1(2), ZERO d2, r1(2), ZERO r2
            const int n = br * 128 + rowX;
            short8 hv = (short8){0, 0, 0, 0, 0, 0, 0, 0};
            const int q4 = t & 3;
            if (n < N && q4 == 0) {
                float2 tp = topic[n];
                unsigned long long f = fwd[n];
                unsigned long long r = rev[n];
                float2 d1 = unpack2(f);
                float2 r1 = unpack2(r);
                hv[0] = (short)f2bf(tp.x); hv[1] = (short)f2bf(tp.y);
                hv[2] = (short)f2bf(d1.x); hv[3] = (short)f2bf(d1.y);
                // hv[4:5] = d2 slot -> 0 (folded into k_edge)
                hv[6] = (short)f2bf(r1.x); hv[7] = (short)f2bf(r1.y);
            }
            *(short8*)((char*)lA[buf] + rowX * 64 + q4 * 16) = hv;
        }
        const char* srcB0 = baseB + (size_t)rowX * (LDKB * 2) + k0 * 2 + colb;
        const char* srcB1 = baseB + (size_t)(rowX + 128) * (LDKB * 2) + k0 * 2 + colb;
        __builtin_amdgcn_global_load_lds((const __attribute__((address_space(1))) void*)srcB0,
                                         (__attribute__((address_space(3))) void*)((char*)lB[buf] + t * 16), 16, 0, 0);
        __builtin_amdgcn_global_load_lds((const __attribute__((address_space(1))) void*)srcB1,
                                         (__attribute__((address_space(3))) void*)((char*)lB[buf] + 8192 + t * 16), 16, 0, 0);
    };

    const int NK = LDKB / 32;  // 9
    stage(0, 0);
    __syncthreads();

    for (int k = 0; k < NK; ++k) {
        const int cur = k & 1;
        if (k + 1 < NK) stage((k + 1) * 32, cur ^ 1);

        short8 af[4], bfr[4];
#pragma unroll
        for (int r = 0; r < 4; ++r) {
            int arow = wr * 64 + r * 16 + (lane & 15);
            af[r] = *(const short8*)(lA[cur] + arow * 32 + (lane >> 4) * 8);
        }
#pragma unroll
        for (int c = 0; c < 4; ++c) {
            int brow = wc * 64 + c * 16 + (lane & 15);
            bfr[c] = *(const short8*)(lB[cur] + brow * 32 + (lane >> 4) * 8);
        }
#pragma unroll
        for (int r = 0; r < 4; ++r)
#pragma unroll
            for (int c = 0; c < 4; ++c)
                acc[r][c] = __builtin_amdgcn_mfma_f32_16x16x32_bf16(af[r], bfr[c], acc[r][c], 0, 0, 0);

        __syncthreads();
    }

    // epilogue: C/D layout col=lane&15, row=(lane>>4)*4+i  (store bf16)
    unsigned short* Pout = bc ? Pt : Ph;
    const int nbase = wc * 64;
    const int mbase = br * 128 + wr * 64 + (lane >> 4) * 4;
#pragma unroll
    for (int r = 0; r < 4; ++r) {
#pragma unroll
        for (int c = 0; c < 4; ++c) {
            int n = nbase + c * 16 + (lane & 15);
#pragma unroll
            for (int i = 0; i < 4; ++i) {
                int m = mbase + r * 16 + i;
                Pout[(size_t)m * EMB + n] = f2bf(acc[r][c][i]);
            }
        }
    }
}

// ---------------- pack per-node {d2, r2} bf16x4 (after r2) ----------------
__global__ void k_pack(const unsigned long long* __restrict__ fwd,
                       const unsigned long long* __restrict__ rev,
                       const unsigned long long* __restrict__ s2,
                       const unsigned long long* __restrict__ sr2,
                       ushort4* __restrict__ dr2, int N, int Mpad) {
    int n = blockIdx.x * blockDim.x + threadIdx.x;
    if (n >= Mpad) return;
    ushort4 v = make_ushort4(0, 0, 0, 0);
    if (n < N) {
        float df = fmaxf((float)(unsigned int)(fwd[n] & 0x3FFULL), 1.0f);
        float dr = fmaxf((float)(unsigned int)(rev[n] & 0x3FFULL), 1.0f);
        float2 d2 = unpack2d(s2[n], df);
        float2 r2 = unpack2d(sr2[n], dr);
        v = make_ushort4(f2bf(d2.x), f2bf(d2.y), f2bf(r2.x), f2bf(r2.y));
    }
    dr2[n] = v;
}

// ---------------- per-edge epilogue + rank-4 d2/r2 fold ----------------
// one wave per edge: lane l covers cols 4l..4l+3 (ushort4, 8B).
__global__ __launch_bounds__(256) void k_edge(
    const int* __restrict__ h_id, const int* __restrict__ r_id, const int* __restrict__ t_id,
    const unsigned short* __restrict__ Ph, const unsigned short* __restrict__ Pt,
    const unsigned short* __restrict__ Prb, const ushort4* __restrict__ dr2,
    const float4* __restrict__ cw, const float* __restrict__ W2,
    const float* __restrict__ b2, float* __restrict__ out, int E) {
    int lane = threadIdx.x & 63;
    int gw = (blockIdx.x * blockDim.x + threadIdx.x) >> 6;
    int nw = (gridDim.x * blockDim.x) >> 6;
    const int lo = 4 * lane;
    float w2c[4];
    *(float4*)w2c = *(const float4*)(W2 + lo);
    float bb = b2[0];
    // rank-4 coefficients for this lane's 4 cols, h-side (j) and t-side (j+256)
    float4 cH[4], cT[4];
#pragma unroll
    for (int c = 0; c < 4; ++c) { cH[c] = cw[lo + c]; cT[c] = cw[256 + lo + c]; }

    for (int e = gw; e < E; e += nw) {
        int h = h_id[e], r = r_id[e], t = t_id[e];
        ushort4 ph = *(const ushort4*)(Ph + (size_t)h * EMB + lo);
        ushort4 pt = *(const ushort4*)(Pt + (size_t)t * EMB + lo);
        ushort4 pr = *(const ushort4*)(Prb + (size_t)r * EMB + lo);
        ushort4 dh = dr2[h];   // {d2x,d2y,r2x,r2y} bf16, L2-resident table
        ushort4 dt = dr2[t];
        float d2hx = bf2f(dh.x), d2hy = bf2f(dh.y), r2hx = bf2f(dh.z), r2hy = bf2f(dh.w);
        float d2tx = bf2f(dt.x), d2ty = bf2f(dt.y), r2tx = bf2f(dt.z), r2ty = bf2f(dt.w);
        const unsigned short* phs = (const unsigned short*)&ph;
        const unsigned short* pts = (const unsigned short*)&pt;
        const unsigned short* prs = (const unsigned short*)&pr;
        float acc = 0.f;
#pragma unroll
        for (int c = 0; c < 4; ++c) {
            float v = bf2f(prs[c]) + bf2f(phs[c]) + bf2f(pts[c]);
            v += d2hx * cH[c].x + d2hy * cH[c].y + r2hx * cH[c].z + r2hy * cH[c].w;
            v += d2tx * cT[c].x + d2ty * cT[c].y + r2tx * cT[c].z + r2ty * cT[c].w;
            acc += fmaxf(v, 0.f) * w2c[c];
        }
#pragma unroll
        for (int m = 32; m >= 1; m >>= 1) acc += __shfl_xor(acc, m, 64);
        if (lane == 0) out[e] = acc + bb;
    }
}

// ---------------- host launch ----------------

extern "C" void kernel_launch(void* const* d_in, const int* in_sizes, int n_in,
                              void* d_out, int out_size, void* d_ws, size_t ws_size,
                              hipStream_t stream) {
    const int*   h_id    = (const int*)d_in[0];
    const int*   r_id    = (const int*)d_in[1];
    const int*   t_id    = (const int*)d_in[2];
    const float* q       = (const float*)d_in[3];
    const float* entity  = (const float*)d_in[4];
    const float* rel     = (const float*)d_in[6];
    const float* topic   = (const float*)d_in[7];
    const float* nontext = (const float*)d_in[8];
    const float* W1      = (const float*)d_in[9];
    const float* b1      = (const float*)d_in[10];
    const float* W2      = (const float*)d_in[11];
    const float* b2      = (const float*)d_in[12];

    const int E      = in_sizes[0];
    const int n_text = in_sizes[4] / EMB;   // 100000
    const int N      = in_sizes[7] / 2;     // 110000
    const int R      = in_sizes[6] / EMB;   // 500
    const int Mpad   = (N + 127) & ~127;    // 110080

    char* p = (char*)d_ws;
    auto alloc = [&](size_t bytes) {
        char* r = p;
        p += (bytes + 255) & ~(size_t)255;
        return r;
    };
    unsigned long long* fwd = (unsigned long long*)alloc((size_t)Mpad * 8);
    unsigned long long* rev = (unsigned long long*)alloc((size_t)Mpad * 8);
    unsigned long long* s2  = (unsigned long long*)alloc((size_t)Mpad * 8);
    unsigned long long* sr2 = (unsigned long long*)alloc((size_t)Mpad * 8);
    size_t zero_bytes = (size_t)(p - (char*)d_ws);
    unsigned short* he  = (unsigned short*)alloc((size_t)Mpad * EMB * 2);
    unsigned short* wT  = (unsigned short*)alloc((size_t)512 * LDKB * 2);
    unsigned short* Prb = (unsigned short*)alloc((size_t)R * EMB * 2);
    unsigned short* Ph  = (unsigned short*)alloc((size_t)Mpad * EMB * 2);
    unsigned short* Pt  = (unsigned short*)alloc((size_t)Mpad * EMB * 2);
    ushort4*        dr2 = (ushort4*)alloc((size_t)Mpad * 8);
    float*          cw  = (float*)alloc((size_t)512 * 4 * 4);

    hipMemsetAsync(d_ws, 0, zero_bytes, stream);

    const int T = 256;
    const int SC1 = (E + T - 1) / T;            // 1954
    const int COPY = Mpad / 4;                  // 27520
    const int WT_BLK = (512 * LDKB) / T;        // 576
    const int COEF = 8;                         // 2048/256
    const int TOTAL1 = SC1 + COPY + WT_BLK + R + COEF;

    k_r1_fused<<<TOTAL1, T, 0, stream>>>(
        h_id, t_id, (const float2*)topic, fwd, rev, E, SC1, COPY, WT_BLK, R, TOTAL1,
        (const float4*)entity, (const float4*)nontext, (ushort4*)he, n_text, N,
        W1, wT, q, rel, b1, Prb, cw);

    const int GB  = (Mpad / 128) * 2;           // 1720 gemm blocks (multiple of 8)
    const int R2B = (E + 511) / 512;            // 977 scatter blocks
    k_gemm_r2<<<GB + R2B, 512, 0, stream>>>(he, wT, Ph, Pt,
                                            (const float2*)topic, fwd, rev, s2, sr2,
                                            h_id, t_id, N, E, GB, GB + R2B);

    k_pack<<<(Mpad + T - 1) / T, T, 0, stream>>>(fwd, rev, s2, sr2, dr2, N, Mpad);

    k_edge<<<4096, T, 0, stream>>>(h_id, r_id, t_id, Ph, Pt, Prb, dr2,
                                   (const float4*)cw, W2, b2, (float*)d_out, E);
}